// Round 1
// baseline (2740.410 us; speedup 1.0000x reference)
//
#include <hip/hip_runtime.h>

#define BM 64
#define BN 64
#define BK 16

// ---------------- copy x into agg (h = x + sum_j x_j) ----------------
__global__ __launch_bounds__(256) void copy4_kernel(const float4* __restrict__ in,
                                                    float4* __restrict__ out, int n4) {
  int i = blockIdx.x * 256 + threadIdx.x;
  if (i < n4) out[i] = in[i];
}

// ---------------- edge scatter: agg[dst] += x[src] ----------------
__global__ __launch_bounds__(256) void edge_scatter_kernel(
    const float* __restrict__ x, const int* __restrict__ src, const int* __restrict__ dst,
    float* __restrict__ agg, int total, int dqShift) {
  int idx = blockIdx.x * 256 + threadIdx.x;
  if (idx >= total) return;
  int e = idx >> dqShift;
  int c = idx & ((1 << dqShift) - 1);
  int s = src[e], d = dst[e];
  float4 v = ((const float4*)x)[((long)s << dqShift) + c];
  float* o = agg + ((((long)d << dqShift) + c) << 2);
  atomicAdd(o + 0, v.x);
  atomicAdd(o + 1, v.y);
  atomicAdd(o + 2, v.z);
  atomicAdd(o + 3, v.w);
}

// ---------------- fp32 tiled GEMM: C = A[MxK] @ B[KxN] + bias ----------------
// optional ReLU; optional BN-stats accumulation (column sum / sumsq -> stats[0..N),[N..2N))
__global__ __launch_bounds__(256) void gemm_kernel(
    const float* __restrict__ A, const float* __restrict__ B,
    const float* __restrict__ bias, float* __restrict__ C,
    int M, int K, int N, int doRelu, float* __restrict__ stats) {
  __shared__ float As[BK][BM + 1];
  __shared__ float Bs[BK][BN];
  const int tid = threadIdx.x;
  const int tx = tid & 15, ty = tid >> 4;
  const int rowBase = blockIdx.x * BM;
  const int colBase = blockIdx.y * BN;
  float acc[4][4] = {};
  for (int k0 = 0; k0 < K; k0 += BK) {
#pragma unroll
    for (int i = 0; i < 4; i++) {
      int l = tid + i * 256;
      int r = l >> 4, kk = l & 15;
      int row = rowBase + r;
      As[kk][r] = (row < M) ? A[(long)row * K + k0 + kk] : 0.f;
    }
#pragma unroll
    for (int i = 0; i < 4; i++) {
      int l = tid + i * 256;
      int kk = l >> 6, c = l & 63;
      Bs[kk][c] = B[(long)(k0 + kk) * N + colBase + c];
    }
    __syncthreads();
#pragma unroll
    for (int kk = 0; kk < BK; kk++) {
      float a[4], b[4];
#pragma unroll
      for (int i = 0; i < 4; i++) a[i] = As[kk][ty * 4 + i];
#pragma unroll
      for (int j = 0; j < 4; j++) b[j] = Bs[kk][tx * 4 + j];
#pragma unroll
      for (int i = 0; i < 4; i++)
#pragma unroll
        for (int j = 0; j < 4; j++) acc[i][j] += a[i] * b[j];
    }
    __syncthreads();
  }
  // epilogue: bias, relu, store, stats
  float4 bv = *(const float4*)(bias + colBase + tx * 4);
  float s1[4] = {0.f, 0.f, 0.f, 0.f}, s2[4] = {0.f, 0.f, 0.f, 0.f};
#pragma unroll
  for (int i = 0; i < 4; i++) {
    int row = rowBase + ty * 4 + i;
    float4 v;
    v.x = acc[i][0] + bv.x;
    v.y = acc[i][1] + bv.y;
    v.z = acc[i][2] + bv.z;
    v.w = acc[i][3] + bv.w;
    if (doRelu) {
      v.x = fmaxf(v.x, 0.f); v.y = fmaxf(v.y, 0.f);
      v.z = fmaxf(v.z, 0.f); v.w = fmaxf(v.w, 0.f);
    }
    if (row < M) {
      *(float4*)(C + (long)row * N + colBase + tx * 4) = v;
      s1[0] += v.x; s1[1] += v.y; s1[2] += v.z; s1[3] += v.w;
      s2[0] += v.x * v.x; s2[1] += v.y * v.y; s2[2] += v.z * v.z; s2[3] += v.w * v.w;
    }
  }
  if (stats) {
    __shared__ float ss[2][BN];
    if (tid < BN) { ss[0][tid] = 0.f; ss[1][tid] = 0.f; }
    __syncthreads();
#pragma unroll
    for (int j = 0; j < 4; j++) {
      atomicAdd(&ss[0][tx * 4 + j], s1[j]);
      atomicAdd(&ss[1][tx * 4 + j], s2[j]);
    }
    __syncthreads();
    if (tid < BN) {
      atomicAdd(&stats[colBase + tid], ss[0][tid]);
      atomicAdd(&stats[N + colBase + tid], ss[1][tid]);
    }
  }
}

// ---------------- BN: fold sums into per-channel scale/shift ----------------
__global__ __launch_bounds__(256) void bn_prep_kernel(float* __restrict__ stats,
                                                      const float* __restrict__ gamma,
                                                      const float* __restrict__ beta,
                                                      int D, float invN) {
  int c = blockIdx.x * 256 + threadIdx.x;
  if (c >= D) return;
  float mean = stats[c] * invN;
  float var = stats[D + c] * invN - mean * mean;
  float sc = rsqrtf(var + 1e-5f) * gamma[c];
  stats[c] = sc;
  stats[D + c] = beta[c] - mean * sc;
}

// ---------------- BN apply + ReLU ----------------
__global__ __launch_bounds__(256) void bn_apply_kernel(
    const float* __restrict__ h, const float* __restrict__ stats,
    float* __restrict__ out, int total4, int D, int dqShift) {
  int idx = blockIdx.x * 256 + threadIdx.x;
  if (idx >= total4) return;
  int c4 = (idx & ((1 << dqShift) - 1)) << 2;
  float4 v = ((const float4*)h)[idx];
  float4 sc = *(const float4*)(stats + c4);
  float4 sh = *(const float4*)(stats + D + c4);
  float4 r;
  r.x = fmaxf(v.x * sc.x + sh.x, 0.f);
  r.y = fmaxf(v.y * sc.y + sh.y, 0.f);
  r.z = fmaxf(v.z * sc.z + sh.z, 0.f);
  r.w = fmaxf(v.w * sc.w + sh.w, 0.f);
  ((float4*)out)[idx] = r;
}

// ---------------- segment-mean pool (batch sorted), D=512 ----------------
__global__ __launch_bounds__(128) void pool_kernel(const float* __restrict__ h,
                                                   const int* __restrict__ batch,
                                                   float* __restrict__ pooled, int N) {
  int g = blockIdx.x;
  __shared__ int s_lo, s_hi;
  if (threadIdx.x == 0) {
    int lo = 0, hi = N;
    while (lo < hi) { int m = (lo + hi) >> 1; if (batch[m] < g) lo = m + 1; else hi = m; }
    s_lo = lo;
    lo = 0; hi = N;
    while (lo < hi) { int m = (lo + hi) >> 1; if (batch[m] < g + 1) lo = m + 1; else hi = m; }
    s_hi = lo;
  }
  __syncthreads();
  int lo = s_lo, hi = s_hi;
  int c = threadIdx.x;  // float4 chunk, 512/4 = 128
  float4 acc = {0.f, 0.f, 0.f, 0.f};
  for (int r = lo; r < hi; r++) {
    float4 v = ((const float4*)h)[(long)r * 128 + c];
    acc.x += v.x; acc.y += v.y; acc.z += v.z; acc.w += v.w;
  }
  int cnt = hi - lo;
  float inv = 1.f / (float)max(cnt, 1);
  acc.x *= inv; acc.y *= inv; acc.z *= inv; acc.w *= inv;
  ((float4*)pooled)[g * 128 + c] = acc;
}

// ---------------- final projection: out = relu(pooled @ wo + bo) ----------------
__global__ __launch_bounds__(64) void out_kernel(const float* __restrict__ pooled,
                                                 const float* __restrict__ wo,
                                                 const float* __restrict__ bo,
                                                 float* __restrict__ out) {
  int g = blockIdx.x, o = threadIdx.x;
  float acc = bo[o];
  for (int c = 0; c < 512; c++) acc += pooled[g * 512 + c] * wo[c * 64 + o];
  out[g * 64 + o] = fmaxf(acc, 0.f);
}

extern "C" void kernel_launch(void* const* d_in, const int* in_sizes, int n_in,
                              void* d_out, int out_size, void* d_ws, size_t ws_size,
                              hipStream_t stream) {
  const float* x0 = (const float*)d_in[0];
  const int* ei = (const int*)d_in[1];
  const int* batch = (const int*)d_in[2];
  const int N = in_sizes[0] / 128;
  const int E = in_sizes[1] / 2;
  const int* src = ei;
  const int* dst = ei + E;
  const float* W[3][6];
  for (int li = 0; li < 3; li++)
    for (int k = 0; k < 6; k++) W[li][k] = (const float*)d_in[3 + li * 6 + k];
  const float* wo = (const float*)d_in[21];
  const float* bo = (const float*)d_in[22];
  float* out = (float*)d_out;

  // workspace layout (floats)
  float* agg = (float*)d_ws;                 // N*256 max
  float* h1 = agg + (size_t)N * 256;         // N*512 (also BN output / next x)
  float* h2 = h1 + (size_t)N * 512;          // N*512
  float* stats = h2 + (size_t)N * 512;       // 1024
  float* pooled = stats + 1024;              // 64*512

  const int dins[3] = {128, 128, 256};
  const int douts[3] = {128, 256, 512};
  const float* xin = x0;
  for (int li = 0; li < 3; li++) {
    int Din = dins[li], Dout = douts[li];
    int dq = Din >> 2;
    int dqs = (dq == 32) ? 5 : (dq == 64) ? 6 : 7;
    int n4 = N * dq;
    copy4_kernel<<<(n4 + 255) / 256, 256, 0, stream>>>((const float4*)xin, (float4*)agg, n4);
    int total = E * dq;
    edge_scatter_kernel<<<(total + 255) / 256, 256, 0, stream>>>(xin, src, dst, agg, total, dqs);
    dim3 g1((N + BM - 1) / BM, Dout / BN);
    gemm_kernel<<<g1, 256, 0, stream>>>(agg, W[li][0], W[li][1], h1, N, Din, Dout, 1, nullptr);
    hipMemsetAsync(stats, 0, 2 * Dout * sizeof(float), stream);
    gemm_kernel<<<g1, 256, 0, stream>>>(h1, W[li][2], W[li][3], h2, N, Dout, Dout, 0, stats);
    bn_prep_kernel<<<(Dout + 255) / 256, 256, 0, stream>>>(stats, W[li][4], W[li][5], Dout, 1.0f / N);
    int odq = Dout >> 2;
    int odqs = (odq == 32) ? 5 : (odq == 64) ? 6 : 7;
    int t4 = N * odq;
    bn_apply_kernel<<<(t4 + 255) / 256, 256, 0, stream>>>(h2, stats, h1, t4, Dout, odqs);
    xin = h1;
  }
  pool_kernel<<<64, 128, 0, stream>>>(h1, batch, pooled, N);
  out_kernel<<<64, 64, 0, stream>>>(pooled, wo, bo, out);
}

// Round 2
// 739.868 us; speedup vs baseline: 3.7039x; 3.7039x over previous
//
#include <hip/hip_runtime.h>

#define BM 64
#define BN 64
#define BK 16

// ================= CSR build =================
__global__ __launch_bounds__(256) void hist_kernel(const int* __restrict__ dst,
                                                   int* __restrict__ deg, int E) {
  int e = blockIdx.x * 256 + threadIdx.x;
  if (e < E) atomicAdd(&deg[dst[e]], 1);
}

// single-block exclusive scan of deg[0..N) -> rowstart[0..N], cursor copy
__global__ __launch_bounds__(1024) void scan_kernel(const int* __restrict__ deg,
                                                    int* __restrict__ rowstart,
                                                    int* __restrict__ cursor, int N) {
  __shared__ int sums[1024];
  const int t = threadIdx.x;
  const int CH = (N + 1023) >> 10;  // <= 32
  int local[32];
  int base = t * CH;
  int s = 0;
  for (int i = 0; i < CH; i++) {
    int idx = base + i;
    int v = (idx < N) ? deg[idx] : 0;
    local[i] = s;
    s += v;
  }
  sums[t] = s;
  __syncthreads();
  for (int off = 1; off < 1024; off <<= 1) {
    int add = (t >= off) ? sums[t - off] : 0;
    __syncthreads();
    sums[t] += add;
    __syncthreads();
  }
  int prefix = sums[t] - s;  // exclusive across threads
  for (int i = 0; i < CH; i++) {
    int idx = base + i;
    if (idx < N) {
      int v = prefix + local[i];
      rowstart[idx] = v;
      cursor[idx] = v;
    }
  }
  if (t == 1023) rowstart[N] = sums[1023];
}

__global__ __launch_bounds__(256) void fill_kernel(const int* __restrict__ src,
                                                   const int* __restrict__ dst,
                                                   int* __restrict__ cursor,
                                                   int* __restrict__ nbr, int E) {
  int e = blockIdx.x * 256 + threadIdx.x;
  if (e >= E) return;
  int pos = atomicAdd(&cursor[dst[e]], 1);
  nbr[pos] = src[e];
}

// ================= gather aggregation: agg[i] = x[i] + sum_nbr x[j] =================
template <int C>  // floats per lane; Din = 64*C
__global__ __launch_bounds__(256) void gather_agg_kernel(
    const float* __restrict__ x, const int* __restrict__ rowstart,
    const int* __restrict__ nbr, float* __restrict__ agg, int N) {
  constexpr int Din = 64 * C;
  const int wave = threadIdx.x >> 6;
  const int lane = threadIdx.x & 63;
  const int node = blockIdx.x * 4 + wave;
  if (node >= N) return;
  float acc[C];
  {
    const float* p = x + (size_t)node * Din + lane * C;
    if constexpr (C == 2) {
      float2 v = *(const float2*)p;
      acc[0] = v.x; acc[1] = v.y;
    } else {
      float4 v = *(const float4*)p;
      acc[0] = v.x; acc[1] = v.y; acc[2] = v.z; acc[3] = v.w;
    }
  }
  const int rs = rowstart[node], re = rowstart[node + 1];
  int e = rs;
  for (; e + 1 < re; e += 2) {
    int s0 = nbr[e], s1 = nbr[e + 1];
    const float* p0 = x + (size_t)s0 * Din + lane * C;
    const float* p1 = x + (size_t)s1 * Din + lane * C;
    if constexpr (C == 2) {
      float2 v0 = *(const float2*)p0, v1 = *(const float2*)p1;
      acc[0] += v0.x; acc[1] += v0.y;
      acc[0] += v1.x; acc[1] += v1.y;
    } else {
      float4 v0 = *(const float4*)p0, v1 = *(const float4*)p1;
      acc[0] += v0.x; acc[1] += v0.y; acc[2] += v0.z; acc[3] += v0.w;
      acc[0] += v1.x; acc[1] += v1.y; acc[2] += v1.z; acc[3] += v1.w;
    }
  }
  if (e < re) {
    int s0 = nbr[e];
    const float* p0 = x + (size_t)s0 * Din + lane * C;
    if constexpr (C == 2) {
      float2 v0 = *(const float2*)p0;
      acc[0] += v0.x; acc[1] += v0.y;
    } else {
      float4 v0 = *(const float4*)p0;
      acc[0] += v0.x; acc[1] += v0.y; acc[2] += v0.z; acc[3] += v0.w;
    }
  }
  float* o = agg + (size_t)node * Din + lane * C;
  if constexpr (C == 2) {
    *(float2*)o = make_float2(acc[0], acc[1]);
  } else {
    *(float4*)o = make_float4(acc[0], acc[1], acc[2], acc[3]);
  }
}

// ================= fp32 tiled GEMM =================
__global__ __launch_bounds__(256) void gemm_kernel(
    const float* __restrict__ A, const float* __restrict__ B,
    const float* __restrict__ bias, float* __restrict__ C,
    int M, int K, int N, int doRelu, float* __restrict__ stats) {
  __shared__ float As[BK][BM + 1];
  __shared__ float Bs[BK][BN];
  const int tid = threadIdx.x;
  const int tx = tid & 15, ty = tid >> 4;
  const int rowBase = blockIdx.x * BM;
  const int colBase = blockIdx.y * BN;
  float acc[4][4] = {};
  for (int k0 = 0; k0 < K; k0 += BK) {
#pragma unroll
    for (int i = 0; i < 4; i++) {
      int l = tid + i * 256;
      int r = l >> 4, kk = l & 15;
      int row = rowBase + r;
      As[kk][r] = (row < M) ? A[(long)row * K + k0 + kk] : 0.f;
    }
#pragma unroll
    for (int i = 0; i < 4; i++) {
      int l = tid + i * 256;
      int kk = l >> 6, c = l & 63;
      Bs[kk][c] = B[(long)(k0 + kk) * N + colBase + c];
    }
    __syncthreads();
#pragma unroll
    for (int kk = 0; kk < BK; kk++) {
      float a[4], b[4];
#pragma unroll
      for (int i = 0; i < 4; i++) a[i] = As[kk][ty * 4 + i];
#pragma unroll
      for (int j = 0; j < 4; j++) b[j] = Bs[kk][tx * 4 + j];
#pragma unroll
      for (int i = 0; i < 4; i++)
#pragma unroll
        for (int j = 0; j < 4; j++) acc[i][j] += a[i] * b[j];
    }
    __syncthreads();
  }
  float4 bv = *(const float4*)(bias + colBase + tx * 4);
  float s1[4] = {0.f, 0.f, 0.f, 0.f}, s2[4] = {0.f, 0.f, 0.f, 0.f};
#pragma unroll
  for (int i = 0; i < 4; i++) {
    int row = rowBase + ty * 4 + i;
    float4 v;
    v.x = acc[i][0] + bv.x;
    v.y = acc[i][1] + bv.y;
    v.z = acc[i][2] + bv.z;
    v.w = acc[i][3] + bv.w;
    if (doRelu) {
      v.x = fmaxf(v.x, 0.f); v.y = fmaxf(v.y, 0.f);
      v.z = fmaxf(v.z, 0.f); v.w = fmaxf(v.w, 0.f);
    }
    if (row < M) {
      *(float4*)(C + (long)row * N + colBase + tx * 4) = v;
      s1[0] += v.x; s1[1] += v.y; s1[2] += v.z; s1[3] += v.w;
      s2[0] += v.x * v.x; s2[1] += v.y * v.y; s2[2] += v.z * v.z; s2[3] += v.w * v.w;
    }
  }
  if (stats) {
    __shared__ float ss[2][BN];
    if (tid < BN) { ss[0][tid] = 0.f; ss[1][tid] = 0.f; }
    __syncthreads();
#pragma unroll
    for (int j = 0; j < 4; j++) {
      atomicAdd(&ss[0][tx * 4 + j], s1[j]);
      atomicAdd(&ss[1][tx * 4 + j], s2[j]);
    }
    __syncthreads();
    if (tid < BN) {
      atomicAdd(&stats[colBase + tid], ss[0][tid]);
      atomicAdd(&stats[N + colBase + tid], ss[1][tid]);
    }
  }
}

// ================= BN fold =================
__global__ __launch_bounds__(256) void bn_prep_kernel(float* __restrict__ stats,
                                                      const float* __restrict__ gamma,
                                                      const float* __restrict__ beta,
                                                      int D, float invN) {
  int c = blockIdx.x * 256 + threadIdx.x;
  if (c >= D) return;
  float mean = stats[c] * invN;
  float var = stats[D + c] * invN - mean * mean;
  float sc = rsqrtf(var + 1e-5f) * gamma[c];
  stats[c] = sc;
  stats[D + c] = beta[c] - mean * sc;
}

// ================= BN apply + ReLU =================
__global__ __launch_bounds__(256) void bn_apply_kernel(
    const float* __restrict__ h, const float* __restrict__ stats,
    float* __restrict__ out, int total4, int D, int dqShift) {
  int idx = blockIdx.x * 256 + threadIdx.x;
  if (idx >= total4) return;
  int c4 = (idx & ((1 << dqShift) - 1)) << 2;
  float4 v = ((const float4*)h)[idx];
  float4 sc = *(const float4*)(stats + c4);
  float4 sh = *(const float4*)(stats + D + c4);
  float4 r;
  r.x = fmaxf(v.x * sc.x + sh.x, 0.f);
  r.y = fmaxf(v.y * sc.y + sh.y, 0.f);
  r.z = fmaxf(v.z * sc.z + sh.z, 0.f);
  r.w = fmaxf(v.w * sc.w + sh.w, 0.f);
  ((float4*)out)[idx] = r;
}

// ================= segment-mean pool =================
__global__ __launch_bounds__(128) void pool_kernel(const float* __restrict__ h,
                                                   const int* __restrict__ batch,
                                                   float* __restrict__ pooled, int N) {
  int g = blockIdx.x;
  __shared__ int s_lo, s_hi;
  if (threadIdx.x == 0) {
    int lo = 0, hi = N;
    while (lo < hi) { int m = (lo + hi) >> 1; if (batch[m] < g) lo = m + 1; else hi = m; }
    s_lo = lo;
    lo = 0; hi = N;
    while (lo < hi) { int m = (lo + hi) >> 1; if (batch[m] < g + 1) lo = m + 1; else hi = m; }
    s_hi = lo;
  }
  __syncthreads();
  int lo = s_lo, hi = s_hi;
  int c = threadIdx.x;
  float4 acc = {0.f, 0.f, 0.f, 0.f};
  for (int r = lo; r < hi; r++) {
    float4 v = ((const float4*)h)[(long)r * 128 + c];
    acc.x += v.x; acc.y += v.y; acc.z += v.z; acc.w += v.w;
  }
  int cnt = hi - lo;
  float inv = 1.f / (float)max(cnt, 1);
  acc.x *= inv; acc.y *= inv; acc.z *= inv; acc.w *= inv;
  ((float4*)pooled)[g * 128 + c] = acc;
}

// ================= final projection =================
__global__ __launch_bounds__(64) void out_kernel(const float* __restrict__ pooled,
                                                 const float* __restrict__ wo,
                                                 const float* __restrict__ bo,
                                                 float* __restrict__ out) {
  int g = blockIdx.x, o = threadIdx.x;
  float acc = bo[o];
  for (int c = 0; c < 512; c++) acc += pooled[g * 512 + c] * wo[c * 64 + o];
  out[g * 64 + o] = fmaxf(acc, 0.f);
}

extern "C" void kernel_launch(void* const* d_in, const int* in_sizes, int n_in,
                              void* d_out, int out_size, void* d_ws, size_t ws_size,
                              hipStream_t stream) {
  const float* x0 = (const float*)d_in[0];
  const int* ei = (const int*)d_in[1];
  const int* batch = (const int*)d_in[2];
  const int N = in_sizes[0] / 128;
  const int E = in_sizes[1] / 2;
  const int* src = ei;
  const int* dst = ei + E;
  const float* W[3][6];
  for (int li = 0; li < 3; li++)
    for (int k = 0; k < 6; k++) W[li][k] = (const float*)d_in[3 + li * 6 + k];
  const float* wo = (const float*)d_in[21];
  const float* bo = (const float*)d_in[22];
  float* out = (float*)d_out;

  // workspace layout
  float* agg = (float*)d_ws;                 // N*256 max
  float* h1 = agg + (size_t)N * 256;         // N*512
  float* h2 = h1 + (size_t)N * 512;          // N*512
  float* stats = h2 + (size_t)N * 512;       // 1024
  float* pooled = stats + 1024;              // 64*512
  int* deg = (int*)(pooled + 64 * 512);      // N
  int* rowstart = deg + N;                   // N+1
  int* cursor = rowstart + N + 1;            // N
  int* nbr = cursor + N;                     // E

  // ---- CSR build (once per call) ----
  hipMemsetAsync(deg, 0, (size_t)N * sizeof(int), stream);
  hist_kernel<<<(E + 255) / 256, 256, 0, stream>>>(dst, deg, E);
  scan_kernel<<<1, 1024, 0, stream>>>(deg, rowstart, cursor, N);
  fill_kernel<<<(E + 255) / 256, 256, 0, stream>>>(src, dst, cursor, nbr, E);

  const int dins[3] = {128, 128, 256};
  const int douts[3] = {128, 256, 512};
  const float* xin = x0;
  for (int li = 0; li < 3; li++) {
    int Din = dins[li], Dout = douts[li];
    int gblocks = (N + 3) / 4;
    if (Din == 128)
      gather_agg_kernel<2><<<gblocks, 256, 0, stream>>>(xin, rowstart, nbr, agg, N);
    else
      gather_agg_kernel<4><<<gblocks, 256, 0, stream>>>(xin, rowstart, nbr, agg, N);
    dim3 g1((N + BM - 1) / BM, Dout / BN);
    gemm_kernel<<<g1, 256, 0, stream>>>(agg, W[li][0], W[li][1], h1, N, Din, Dout, 1, nullptr);
    hipMemsetAsync(stats, 0, 2 * Dout * sizeof(float), stream);
    gemm_kernel<<<g1, 256, 0, stream>>>(h1, W[li][2], W[li][3], h2, N, Dout, Dout, 0, stats);
    bn_prep_kernel<<<(Dout + 255) / 256, 256, 0, stream>>>(stats, W[li][4], W[li][5], Dout, 1.0f / N);
    int odq = Dout >> 2;
    int odqs = (odq == 32) ? 5 : (odq == 64) ? 6 : 7;
    int t4 = N * odq;
    bn_apply_kernel<<<(t4 + 255) / 256, 256, 0, stream>>>(h2, stats, h1, t4, Dout, odqs);
    xin = h1;
  }
  pool_kernel<<<64, 128, 0, stream>>>(h1, batch, pooled, N);
  out_kernel<<<64, 64, 0, stream>>>(pooled, wo, bo, out);
}

// Round 3
// 616.859 us; speedup vs baseline: 4.4425x; 1.1994x over previous
//
#include <hip/hip_runtime.h>

typedef float f32x4 __attribute__((ext_vector_type(4)));
typedef short bf16x8 __attribute__((ext_vector_type(8)));

__device__ __forceinline__ unsigned short bf16r(float f) {
  unsigned int u = __float_as_uint(f);
  return (unsigned short)((u + 0x7FFFu + ((u >> 16) & 1u)) >> 16);
}
__device__ __forceinline__ float bf2f(unsigned short h) {
  return __uint_as_float((unsigned int)h << 16);
}

// ================= CSR build =================
__global__ __launch_bounds__(256) void hist_kernel(const int* __restrict__ dst,
                                                   int* __restrict__ deg, int E) {
  int e = blockIdx.x * 256 + threadIdx.x;
  if (e < E) atomicAdd(&deg[dst[e]], 1);
}

__global__ __launch_bounds__(1024) void scan_kernel(const int* __restrict__ deg,
                                                    int* __restrict__ rowstart,
                                                    int* __restrict__ cursor, int N) {
  __shared__ int sums[1024];
  const int t = threadIdx.x;
  const int CH = (N + 1023) >> 10;
  int local[32];
  int base = t * CH;
  int s = 0;
  for (int i = 0; i < CH; i++) {
    int idx = base + i;
    int v = (idx < N) ? deg[idx] : 0;
    local[i] = s;
    s += v;
  }
  sums[t] = s;
  __syncthreads();
  for (int off = 1; off < 1024; off <<= 1) {
    int add = (t >= off) ? sums[t - off] : 0;
    __syncthreads();
    sums[t] += add;
    __syncthreads();
  }
  int prefix = sums[t] - s;
  for (int i = 0; i < CH; i++) {
    int idx = base + i;
    if (idx < N) {
      int v = prefix + local[i];
      rowstart[idx] = v;
      cursor[idx] = v;
    }
  }
  if (t == 1023) rowstart[N] = sums[1023];
}

__global__ __launch_bounds__(256) void fill_kernel(const int* __restrict__ src,
                                                   const int* __restrict__ dst,
                                                   int* __restrict__ cursor,
                                                   int* __restrict__ nbr, int E) {
  int e = blockIdx.x * 256 + threadIdx.x;
  if (e >= E) return;
  int pos = atomicAdd(&cursor[dst[e]], 1);
  nbr[pos] = src[e];
}

// ================= gather aggregation =================
template <int C>
__global__ __launch_bounds__(256) void gather_agg_kernel(
    const float* __restrict__ x, const int* __restrict__ rowstart,
    const int* __restrict__ nbr, float* __restrict__ agg, int N) {
  constexpr int Din = 64 * C;
  const int wave = threadIdx.x >> 6;
  const int lane = threadIdx.x & 63;
  const int node = blockIdx.x * 4 + wave;
  if (node >= N) return;
  float acc[C];
  {
    const float* p = x + (size_t)node * Din + lane * C;
    if constexpr (C == 2) {
      float2 v = *(const float2*)p;
      acc[0] = v.x; acc[1] = v.y;
    } else {
      float4 v = *(const float4*)p;
      acc[0] = v.x; acc[1] = v.y; acc[2] = v.z; acc[3] = v.w;
    }
  }
  const int rs = rowstart[node], re = rowstart[node + 1];
  for (int e = rs; e < re; e++) {
    int s0 = nbr[e];
    const float* p0 = x + (size_t)s0 * Din + lane * C;
    if constexpr (C == 2) {
      float2 v0 = *(const float2*)p0;
      acc[0] += v0.x; acc[1] += v0.y;
    } else {
      float4 v0 = *(const float4*)p0;
      acc[0] += v0.x; acc[1] += v0.y; acc[2] += v0.z; acc[3] += v0.w;
    }
  }
  float* o = agg + (size_t)node * Din + lane * C;
  if constexpr (C == 2) {
    *(float2*)o = make_float2(acc[0], acc[1]);
  } else {
    *(float4*)o = make_float4(acc[0], acc[1], acc[2], acc[3]);
  }
}

// ================= weight prep: W[K][N] fp32 -> WT_hi/lo [N][K] bf16 =================
__global__ __launch_bounds__(256) void wprep_kernel(const float* __restrict__ W,
                                                    unsigned short* __restrict__ TH,
                                                    unsigned short* __restrict__ TL,
                                                    int K, int N) {
  int idx = blockIdx.x * 256 + threadIdx.x;
  if (idx >= K * N) return;
  int k = idx / N, n = idx - k * N;
  float v = W[idx];
  unsigned short h = bf16r(v);
  TH[(size_t)n * K + k] = h;
  TL[(size_t)n * K + k] = bf16r(v - bf2f(h));
}

// ================= MFMA GEMM: C = A[MxK] @ B[KxN] + bias, split-bf16 =================
// B given pre-transposed/converted: BT_hi/BT_lo [N][K] bf16.
// Tile 64x64, BK=64, 4 waves; A staged in LDS fragment-linear (hi/lo).
__global__ __launch_bounds__(256) void gemm_mfma_kernel(
    const float* __restrict__ A, const unsigned short* __restrict__ BT_hi,
    const unsigned short* __restrict__ BT_lo, const float* __restrict__ bias,
    float* __restrict__ C, int M, int K, int N, int doRelu, float* __restrict__ stats) {
  __shared__ unsigned short Ah[8 * 512];
  __shared__ unsigned short Al[8 * 512];
  const int tid = threadIdx.x;
  const int lane = tid & 63;
  const int w = tid >> 6;
  const int wr = w >> 1, wc = w & 1;
  const int rowBase = blockIdx.y * 64;
  const int colBase = blockIdx.x * 64 + wc * 32;

  f32x4 acc[2][2] = {};  // [fi][cf]

  const int c0 = colBase + (lane & 15);
  const int kfrag = (lane >> 4) * 8;
  const int srow = tid >> 2;  // staging row 0..63
  const int schunk = tid & 3;
  const size_t arowOff = (size_t)(rowBase + srow) * K;
  const bool srowOk = (rowBase + srow) < M;
  // LDS write slot (same for both iterations, frag differs by iteration)
  const int slane = (srow & 15) | (schunk << 4);
  const int sfrag = srow >> 4;  // 0..3

  for (int k0 = 0; k0 < K; k0 += 64) {
#pragma unroll
    for (int i = 0; i < 2; i++) {
      int kk = k0 + schunk * 8 + i * 32;
      float v[8];
      if (srowOk) {
        float4 a = *(const float4*)(A + arowOff + kk);
        float4 b = *(const float4*)(A + arowOff + kk + 4);
        v[0] = a.x; v[1] = a.y; v[2] = a.z; v[3] = a.w;
        v[4] = b.x; v[5] = b.y; v[6] = b.z; v[7] = b.w;
      } else {
#pragma unroll
        for (int j = 0; j < 8; j++) v[j] = 0.f;
      }
      bf16x8 h8, l8;
#pragma unroll
      for (int j = 0; j < 8; j++) {
        unsigned short h = bf16r(v[j]);
        h8[j] = (short)h;
        l8[j] = (short)bf16r(v[j] - bf2f(h));
      }
      int frag = i * 4 + sfrag;
      *(bf16x8*)(Ah + frag * 512 + slane * 8) = h8;
      *(bf16x8*)(Al + frag * 512 + slane * 8) = l8;
    }
    __syncthreads();
#pragma unroll
    for (int ks = 0; ks < 2; ks++) {
      int kidx = k0 + ks * 32 + kfrag;
      bf16x8 bh0 = *(const bf16x8*)(BT_hi + (size_t)c0 * K + kidx);
      bf16x8 bl0 = *(const bf16x8*)(BT_lo + (size_t)c0 * K + kidx);
      bf16x8 bh1 = *(const bf16x8*)(BT_hi + (size_t)(c0 + 16) * K + kidx);
      bf16x8 bl1 = *(const bf16x8*)(BT_lo + (size_t)(c0 + 16) * K + kidx);
#pragma unroll
      for (int fi = 0; fi < 2; fi++) {
        int frag = ks * 4 + wr * 2 + fi;
        bf16x8 ah = *(const bf16x8*)(Ah + frag * 512 + lane * 8);
        bf16x8 al = *(const bf16x8*)(Al + frag * 512 + lane * 8);
        acc[fi][0] = __builtin_amdgcn_mfma_f32_16x16x32_bf16(ah, bh0, acc[fi][0], 0, 0, 0);
        acc[fi][0] = __builtin_amdgcn_mfma_f32_16x16x32_bf16(al, bh0, acc[fi][0], 0, 0, 0);
        acc[fi][0] = __builtin_amdgcn_mfma_f32_16x16x32_bf16(ah, bl0, acc[fi][0], 0, 0, 0);
        acc[fi][1] = __builtin_amdgcn_mfma_f32_16x16x32_bf16(ah, bh1, acc[fi][1], 0, 0, 0);
        acc[fi][1] = __builtin_amdgcn_mfma_f32_16x16x32_bf16(al, bh1, acc[fi][1], 0, 0, 0);
        acc[fi][1] = __builtin_amdgcn_mfma_f32_16x16x32_bf16(ah, bl1, acc[fi][1], 0, 0, 0);
      }
    }
    __syncthreads();
  }

  // epilogue
  const float bias0 = bias[c0], bias1 = bias[c0 + 16];
  float s1[2] = {0.f, 0.f}, s2[2] = {0.f, 0.f};
  const int rbase = rowBase + wr * 32 + (lane >> 4) * 4;
#pragma unroll
  for (int fi = 0; fi < 2; fi++) {
#pragma unroll
    for (int j = 0; j < 4; j++) {
      int row = rbase + fi * 16 + j;
      float v0 = acc[fi][0][j] + bias0;
      float v1 = acc[fi][1][j] + bias1;
      if (doRelu) { v0 = fmaxf(v0, 0.f); v1 = fmaxf(v1, 0.f); }
      if (row < M) {
        C[(size_t)row * N + c0] = v0;
        C[(size_t)row * N + c0 + 16] = v1;
        s1[0] += v0; s2[0] += v0 * v0;
        s1[1] += v1; s2[1] += v1 * v1;
      }
    }
  }
  if (stats) {
#pragma unroll
    for (int off = 16; off < 64; off <<= 1) {
      s1[0] += __shfl_xor(s1[0], off);
      s2[0] += __shfl_xor(s2[0], off);
      s1[1] += __shfl_xor(s1[1], off);
      s2[1] += __shfl_xor(s2[1], off);
    }
    if (lane < 16) {
      atomicAdd(&stats[c0], s1[0]);
      atomicAdd(&stats[N + c0], s2[0]);
      atomicAdd(&stats[c0 + 16], s1[1]);
      atomicAdd(&stats[N + c0 + 16], s2[1]);
    }
  }
}

// ================= BN fold =================
__global__ __launch_bounds__(256) void bn_prep_kernel(float* __restrict__ stats,
                                                      const float* __restrict__ gamma,
                                                      const float* __restrict__ beta,
                                                      int D, float invN) {
  int c = blockIdx.x * 256 + threadIdx.x;
  if (c >= D) return;
  float mean = stats[c] * invN;
  float var = stats[D + c] * invN - mean * mean;
  float sc = rsqrtf(var + 1e-5f) * gamma[c];
  stats[c] = sc;
  stats[D + c] = beta[c] - mean * sc;
}

// ================= BN apply + ReLU =================
__global__ __launch_bounds__(256) void bn_apply_kernel(
    const float* __restrict__ h, const float* __restrict__ stats,
    float* __restrict__ out, int total4, int D, int dqShift) {
  int idx = blockIdx.x * 256 + threadIdx.x;
  if (idx >= total4) return;
  int c4 = (idx & ((1 << dqShift) - 1)) << 2;
  float4 v = ((const float4*)h)[idx];
  float4 sc = *(const float4*)(stats + c4);
  float4 sh = *(const float4*)(stats + D + c4);
  float4 r;
  r.x = fmaxf(v.x * sc.x + sh.x, 0.f);
  r.y = fmaxf(v.y * sc.y + sh.y, 0.f);
  r.z = fmaxf(v.z * sc.z + sh.z, 0.f);
  r.w = fmaxf(v.w * sc.w + sh.w, 0.f);
  ((float4*)out)[idx] = r;
}

// ================= segment-mean pool =================
__global__ __launch_bounds__(128) void pool_kernel(const float* __restrict__ h,
                                                   const int* __restrict__ batch,
                                                   float* __restrict__ pooled, int N) {
  int g = blockIdx.x;
  __shared__ int s_lo, s_hi;
  if (threadIdx.x == 0) {
    int lo = 0, hi = N;
    while (lo < hi) { int m = (lo + hi) >> 1; if (batch[m] < g) lo = m + 1; else hi = m; }
    s_lo = lo;
    lo = 0; hi = N;
    while (lo < hi) { int m = (lo + hi) >> 1; if (batch[m] < g + 1) lo = m + 1; else hi = m; }
    s_hi = lo;
  }
  __syncthreads();
  int lo = s_lo, hi = s_hi;
  int c = threadIdx.x;
  float4 acc = {0.f, 0.f, 0.f, 0.f};
  for (int r = lo; r < hi; r++) {
    float4 v = ((const float4*)h)[(long)r * 128 + c];
    acc.x += v.x; acc.y += v.y; acc.z += v.z; acc.w += v.w;
  }
  int cnt = hi - lo;
  float inv = 1.f / (float)max(cnt, 1);
  acc.x *= inv; acc.y *= inv; acc.z *= inv; acc.w *= inv;
  ((float4*)pooled)[g * 128 + c] = acc;
}

// ================= final projection =================
__global__ __launch_bounds__(64) void out_kernel(const float* __restrict__ pooled,
                                                 const float* __restrict__ wo,
                                                 const float* __restrict__ bo,
                                                 float* __restrict__ out) {
  int g = blockIdx.x, o = threadIdx.x;
  float acc = bo[o];
  for (int c = 0; c < 512; c++) acc += pooled[g * 512 + c] * wo[c * 64 + o];
  out[g * 64 + o] = fmaxf(acc, 0.f);
}

extern "C" void kernel_launch(void* const* d_in, const int* in_sizes, int n_in,
                              void* d_out, int out_size, void* d_ws, size_t ws_size,
                              hipStream_t stream) {
  const float* x0 = (const float*)d_in[0];
  const int* ei = (const int*)d_in[1];
  const int* batch = (const int*)d_in[2];
  const int N = in_sizes[0] / 128;
  const int E = in_sizes[1] / 2;
  const int* src = ei;
  const int* dst = ei + E;
  const float* W[3][6];
  for (int li = 0; li < 3; li++)
    for (int k = 0; k < 6; k++) W[li][k] = (const float*)d_in[3 + li * 6 + k];
  const float* wo = (const float*)d_in[21];
  const float* bo = (const float*)d_in[22];
  float* out = (float*)d_out;

  // workspace layout
  float* agg = (float*)d_ws;                 // N*256
  float* h1 = agg + (size_t)N * 256;         // N*512
  float* h2 = h1 + (size_t)N * 512;          // N*512
  float* stats = h2 + (size_t)N * 512;       // 1024
  float* pooled = stats + 1024;              // 64*512
  int* deg = (int*)(pooled + 64 * 512);      // N
  int* rowstart = deg + N;                   // N+1
  int* cursor = rowstart + N + 1;            // N
  int* nbr = cursor + N;                     // E
  uintptr_t wp = (uintptr_t)(nbr + E);
  wp = (wp + 15) & ~(uintptr_t)15;
  unsigned short* wbuf = (unsigned short*)wp;

  const int dins[3] = {128, 128, 256};
  const int douts[3] = {128, 256, 512};

  // weight prep (converted hi/lo transposed tables)
  unsigned short* WT[3][4];  // [li][th1, tl1, th2, tl2]
  {
    unsigned short* p = wbuf;
    for (int li = 0; li < 3; li++) {
      size_t s1 = (size_t)dins[li] * douts[li];
      size_t s2 = (size_t)douts[li] * douts[li];
      WT[li][0] = p; p += s1;
      WT[li][1] = p; p += s1;
      WT[li][2] = p; p += s2;
      WT[li][3] = p; p += s2;
    }
  }
  for (int li = 0; li < 3; li++) {
    int e1 = dins[li] * douts[li];
    int e2 = douts[li] * douts[li];
    wprep_kernel<<<(e1 + 255) / 256, 256, 0, stream>>>(W[li][0], WT[li][0], WT[li][1], dins[li], douts[li]);
    wprep_kernel<<<(e2 + 255) / 256, 256, 0, stream>>>(W[li][2], WT[li][2], WT[li][3], douts[li], douts[li]);
  }

  // CSR build
  hipMemsetAsync(deg, 0, (size_t)N * sizeof(int), stream);
  hist_kernel<<<(E + 255) / 256, 256, 0, stream>>>(dst, deg, E);
  scan_kernel<<<1, 1024, 0, stream>>>(deg, rowstart, cursor, N);
  fill_kernel<<<(E + 255) / 256, 256, 0, stream>>>(src, dst, cursor, nbr, E);

  const float* xin = x0;
  const int mblocks = (N + 63) / 64;
  for (int li = 0; li < 3; li++) {
    int Din = dins[li], Dout = douts[li];
    int gblocks = (N + 3) / 4;
    if (Din == 128)
      gather_agg_kernel<2><<<gblocks, 256, 0, stream>>>(xin, rowstart, nbr, agg, N);
    else
      gather_agg_kernel<4><<<gblocks, 256, 0, stream>>>(xin, rowstart, nbr, agg, N);
    dim3 g1(Dout / 64, mblocks);
    gemm_mfma_kernel<<<g1, 256, 0, stream>>>(agg, WT[li][0], WT[li][1], W[li][1], h1,
                                             N, Din, Dout, 1, nullptr);
    hipMemsetAsync(stats, 0, 2 * Dout * sizeof(float), stream);
    gemm_mfma_kernel<<<g1, 256, 0, stream>>>(h1, WT[li][2], WT[li][3], W[li][3], h2,
                                             N, Dout, Dout, 0, stats);
    bn_prep_kernel<<<(Dout + 255) / 256, 256, 0, stream>>>(stats, W[li][4], W[li][5], Dout, 1.0f / N);
    int odq = Dout >> 2;
    int odqs = (odq == 32) ? 5 : (odq == 64) ? 6 : 7;
    int t4 = N * odq;
    bn_apply_kernel<<<(t4 + 255) / 256, 256, 0, stream>>>(h2, stats, h1, t4, Dout, odqs);
    xin = h1;
  }
  pool_kernel<<<64, 128, 0, stream>>>(h1, batch, pooled, N);
  out_kernel<<<64, 64, 0, stream>>>(pooled, wo, bo, out);
}

// Round 4
// 515.937 us; speedup vs baseline: 5.3115x; 1.1956x over previous
//
#include <hip/hip_runtime.h>

typedef float f32x4 __attribute__((ext_vector_type(4)));
typedef short bf16x8 __attribute__((ext_vector_type(8)));

__device__ __forceinline__ unsigned short bf16r(float f) {
  unsigned int u = __float_as_uint(f);
  return (unsigned short)((u + 0x7FFFu + ((u >> 16) & 1u)) >> 16);
}
__device__ __forceinline__ float bf2f(unsigned short h) {
  return __uint_as_float((unsigned int)h << 16);
}

// ================= CSR build =================
__global__ __launch_bounds__(256) void hist_kernel(const int* __restrict__ dst,
                                                   int* __restrict__ deg, int E) {
  int e = blockIdx.x * 256 + threadIdx.x;
  if (e < E) atomicAdd(&deg[dst[e]], 1);
}

__global__ __launch_bounds__(1024) void scan_kernel(const int* __restrict__ deg,
                                                    int* __restrict__ rowstart,
                                                    int* __restrict__ cursor, int N) {
  __shared__ int sums[1024];
  const int t = threadIdx.x;
  const int CH = (N + 1023) >> 10;
  int local[32];
  int base = t * CH;
  int s = 0;
  for (int i = 0; i < CH; i++) {
    int idx = base + i;
    int v = (idx < N) ? deg[idx] : 0;
    local[i] = s;
    s += v;
  }
  sums[t] = s;
  __syncthreads();
  for (int off = 1; off < 1024; off <<= 1) {
    int add = (t >= off) ? sums[t - off] : 0;
    __syncthreads();
    sums[t] += add;
    __syncthreads();
  }
  int prefix = sums[t] - s;
  for (int i = 0; i < CH; i++) {
    int idx = base + i;
    if (idx < N) {
      int v = prefix + local[i];
      rowstart[idx] = v;
      cursor[idx] = v;
    }
  }
  if (t == 1023) rowstart[N] = sums[1023];
}

__global__ __launch_bounds__(256) void fill_kernel(const int* __restrict__ src,
                                                   const int* __restrict__ dst,
                                                   int* __restrict__ cursor,
                                                   int* __restrict__ nbr, int E) {
  int e = blockIdx.x * 256 + threadIdx.x;
  if (e >= E) return;
  int pos = atomicAdd(&cursor[dst[e]], 1);
  nbr[pos] = src[e];
}

// ================= gather aggregation =================
template <int C>
__global__ __launch_bounds__(256) void gather_agg_kernel(
    const float* __restrict__ x, const int* __restrict__ rowstart,
    const int* __restrict__ nbr, float* __restrict__ agg, int N) {
  constexpr int Din = 64 * C;
  const int wave = threadIdx.x >> 6;
  const int lane = threadIdx.x & 63;
  const int node = blockIdx.x * 4 + wave;
  if (node >= N) return;
  float acc[C];
  {
    const float* p = x + (size_t)node * Din + lane * C;
    if constexpr (C == 2) {
      float2 v = *(const float2*)p;
      acc[0] = v.x; acc[1] = v.y;
    } else {
      float4 v = *(const float4*)p;
      acc[0] = v.x; acc[1] = v.y; acc[2] = v.z; acc[3] = v.w;
    }
  }
  const int rs = rowstart[node], re = rowstart[node + 1];
  for (int e = rs; e < re; e++) {
    int s0 = nbr[e];
    const float* p0 = x + (size_t)s0 * Din + lane * C;
    if constexpr (C == 2) {
      float2 v0 = *(const float2*)p0;
      acc[0] += v0.x; acc[1] += v0.y;
    } else {
      float4 v0 = *(const float4*)p0;
      acc[0] += v0.x; acc[1] += v0.y; acc[2] += v0.z; acc[3] += v0.w;
    }
  }
  float* o = agg + (size_t)node * Din + lane * C;
  if constexpr (C == 2) {
    *(float2*)o = make_float2(acc[0], acc[1]);
  } else {
    *(float4*)o = make_float4(acc[0], acc[1], acc[2], acc[3]);
  }
}

// ================= weight prep: W[K][N] fp32 -> WT_hi/lo [N][K] bf16 =================
__global__ __launch_bounds__(256) void wprep_kernel(const float* __restrict__ W,
                                                    unsigned short* __restrict__ TH,
                                                    unsigned short* __restrict__ TL,
                                                    int K, int N) {
  int idx = blockIdx.x * 256 + threadIdx.x;
  if (idx >= K * N) return;
  int k = idx / N, n = idx - k * N;
  float v = W[idx];
  unsigned short h = bf16r(v);
  TH[(size_t)n * K + k] = h;
  TL[(size_t)n * K + k] = bf16r(v - bf2f(h));
}

// ================= MFMA GEMM: C = A[MxK] @ B[KxN] + bias, split-bf16 =================
// Tile 64 rows x 128 cols, BK=64, 4 waves (wave = 32 cols x 64 rows).
// 1-D grid with XCD-aware swizzle: all col-blocks of a row panel land on one XCD.
__global__ __launch_bounds__(256) void gemm_mfma_kernel(
    const float* __restrict__ A, const unsigned short* __restrict__ BT_hi,
    const unsigned short* __restrict__ BT_lo, const float* __restrict__ bias,
    float* __restrict__ C, int M, int K, int N, int mblocks, int cbShift,
    int doRelu, float* __restrict__ stats) {
  __shared__ unsigned short Ah[8 * 512];
  __shared__ unsigned short Al[8 * 512];
  const int bid = blockIdx.x;
  const int xcd = bid & 7;
  const int q = bid >> 3;
  const int r = ((q >> cbShift) << 3) + xcd;
  const int cb = q & ((1 << cbShift) - 1);
  if (r >= mblocks) return;

  const int tid = threadIdx.x;
  const int lane = tid & 63;
  const int w = tid >> 6;
  const int rowBase = r * 64;
  const int colBase = cb * 128 + w * 32;

  f32x4 acc[4][2] = {};  // [row-frag][col-frag]

  const int c0 = colBase + (lane & 15);
  const int kfrag = (lane >> 4) * 8;
  const int srow = tid >> 2;
  const int schunk = tid & 3;
  const size_t arowOff = (size_t)(rowBase + srow) * K;
  const bool srowOk = (rowBase + srow) < M;
  const int slane = (srow & 15) | (schunk << 4);
  const int sfrag = srow >> 4;

  for (int k0 = 0; k0 < K; k0 += 64) {
#pragma unroll
    for (int i = 0; i < 2; i++) {
      int kk = k0 + schunk * 8 + i * 32;
      float v[8];
      if (srowOk) {
        float4 a = *(const float4*)(A + arowOff + kk);
        float4 b = *(const float4*)(A + arowOff + kk + 4);
        v[0] = a.x; v[1] = a.y; v[2] = a.z; v[3] = a.w;
        v[4] = b.x; v[5] = b.y; v[6] = b.z; v[7] = b.w;
      } else {
#pragma unroll
        for (int j = 0; j < 8; j++) v[j] = 0.f;
      }
      bf16x8 h8, l8;
#pragma unroll
      for (int j = 0; j < 8; j++) {
        unsigned short h = bf16r(v[j]);
        h8[j] = (short)h;
        l8[j] = (short)bf16r(v[j] - bf2f(h));
      }
      int frag = i * 4 + sfrag;
      *(bf16x8*)(Ah + frag * 512 + slane * 8) = h8;
      *(bf16x8*)(Al + frag * 512 + slane * 8) = l8;
    }
    __syncthreads();
#pragma unroll
    for (int ks = 0; ks < 2; ks++) {
      int kidx = k0 + ks * 32 + kfrag;
      bf16x8 bh0 = *(const bf16x8*)(BT_hi + (size_t)c0 * K + kidx);
      bf16x8 bl0 = *(const bf16x8*)(BT_lo + (size_t)c0 * K + kidx);
      bf16x8 bh1 = *(const bf16x8*)(BT_hi + (size_t)(c0 + 16) * K + kidx);
      bf16x8 bl1 = *(const bf16x8*)(BT_lo + (size_t)(c0 + 16) * K + kidx);
#pragma unroll
      for (int fi = 0; fi < 4; fi++) {
        int frag = ks * 4 + fi;
        bf16x8 ah = *(const bf16x8*)(Ah + frag * 512 + lane * 8);
        bf16x8 al = *(const bf16x8*)(Al + frag * 512 + lane * 8);
        acc[fi][0] = __builtin_amdgcn_mfma_f32_16x16x32_bf16(ah, bh0, acc[fi][0], 0, 0, 0);
        acc[fi][0] = __builtin_amdgcn_mfma_f32_16x16x32_bf16(al, bh0, acc[fi][0], 0, 0, 0);
        acc[fi][0] = __builtin_amdgcn_mfma_f32_16x16x32_bf16(ah, bl0, acc[fi][0], 0, 0, 0);
        acc[fi][1] = __builtin_amdgcn_mfma_f32_16x16x32_bf16(ah, bh1, acc[fi][1], 0, 0, 0);
        acc[fi][1] = __builtin_amdgcn_mfma_f32_16x16x32_bf16(al, bh1, acc[fi][1], 0, 0, 0);
        acc[fi][1] = __builtin_amdgcn_mfma_f32_16x16x32_bf16(ah, bl1, acc[fi][1], 0, 0, 0);
      }
    }
    __syncthreads();
  }

  // epilogue
  const float bias0 = bias[c0], bias1 = bias[c0 + 16];
  float s1[2] = {0.f, 0.f}, s2[2] = {0.f, 0.f};
  const int rbase = rowBase + (lane >> 4) * 4;
#pragma unroll
  for (int fi = 0; fi < 4; fi++) {
#pragma unroll
    for (int j = 0; j < 4; j++) {
      int row = rbase + fi * 16 + j;
      float v0 = acc[fi][0][j] + bias0;
      float v1 = acc[fi][1][j] + bias1;
      if (doRelu) { v0 = fmaxf(v0, 0.f); v1 = fmaxf(v1, 0.f); }
      if (row < M) {
        C[(size_t)row * N + c0] = v0;
        C[(size_t)row * N + c0 + 16] = v1;
        s1[0] += v0; s2[0] += v0 * v0;
        s1[1] += v1; s2[1] += v1 * v1;
      }
    }
  }
  if (stats) {
#pragma unroll
    for (int off = 16; off < 64; off <<= 1) {
      s1[0] += __shfl_xor(s1[0], off);
      s2[0] += __shfl_xor(s2[0], off);
      s1[1] += __shfl_xor(s1[1], off);
      s2[1] += __shfl_xor(s2[1], off);
    }
    if (lane < 16) {
      atomicAdd(&stats[c0], s1[0]);
      atomicAdd(&stats[N + c0], s2[0]);
      atomicAdd(&stats[c0 + 16], s1[1]);
      atomicAdd(&stats[N + c0 + 16], s2[1]);
    }
  }
}

// ================= BN fold =================
__global__ __launch_bounds__(256) void bn_prep_kernel(float* __restrict__ stats,
                                                      const float* __restrict__ gamma,
                                                      const float* __restrict__ beta,
                                                      int D, float invN) {
  int c = blockIdx.x * 256 + threadIdx.x;
  if (c >= D) return;
  float mean = stats[c] * invN;
  float var = stats[D + c] * invN - mean * mean;
  float sc = rsqrtf(var + 1e-5f) * gamma[c];
  stats[c] = sc;
  stats[D + c] = beta[c] - mean * sc;
}

// ================= BN apply + ReLU =================
__global__ __launch_bounds__(256) void bn_apply_kernel(
    const float* __restrict__ h, const float* __restrict__ stats,
    float* __restrict__ out, int total4, int D, int dqShift) {
  int idx = blockIdx.x * 256 + threadIdx.x;
  if (idx >= total4) return;
  int c4 = (idx & ((1 << dqShift) - 1)) << 2;
  float4 v = ((const float4*)h)[idx];
  float4 sc = *(const float4*)(stats + c4);
  float4 sh = *(const float4*)(stats + D + c4);
  float4 r;
  r.x = fmaxf(v.x * sc.x + sh.x, 0.f);
  r.y = fmaxf(v.y * sc.y + sh.y, 0.f);
  r.z = fmaxf(v.z * sc.z + sh.z, 0.f);
  r.w = fmaxf(v.w * sc.w + sh.w, 0.f);
  ((float4*)out)[idx] = r;
}

// ================= segment-mean pool =================
__global__ __launch_bounds__(128) void pool_kernel(const float* __restrict__ h,
                                                   const int* __restrict__ batch,
                                                   float* __restrict__ pooled, int N) {
  int g = blockIdx.x;
  __shared__ int s_lo, s_hi;
  if (threadIdx.x == 0) {
    int lo = 0, hi = N;
    while (lo < hi) { int m = (lo + hi) >> 1; if (batch[m] < g) lo = m + 1; else hi = m; }
    s_lo = lo;
    lo = 0; hi = N;
    while (lo < hi) { int m = (lo + hi) >> 1; if (batch[m] < g + 1) lo = m + 1; else hi = m; }
    s_hi = lo;
  }
  __syncthreads();
  int lo = s_lo, hi = s_hi;
  int c = threadIdx.x;
  float4 acc = {0.f, 0.f, 0.f, 0.f};
  for (int r = lo; r < hi; r++) {
    float4 v = ((const float4*)h)[(long)r * 128 + c];
    acc.x += v.x; acc.y += v.y; acc.z += v.z; acc.w += v.w;
  }
  int cnt = hi - lo;
  float inv = 1.f / (float)max(cnt, 1);
  acc.x *= inv; acc.y *= inv; acc.z *= inv; acc.w *= inv;
  ((float4*)pooled)[g * 128 + c] = acc;
}

// ================= final projection =================
__global__ __launch_bounds__(64) void out_kernel(const float* __restrict__ pooled,
                                                 const float* __restrict__ wo,
                                                 const float* __restrict__ bo,
                                                 float* __restrict__ out) {
  int g = blockIdx.x, o = threadIdx.x;
  float acc = bo[o];
  for (int c = 0; c < 512; c++) acc += pooled[g * 512 + c] * wo[c * 64 + o];
  out[g * 64 + o] = fmaxf(acc, 0.f);
}

extern "C" void kernel_launch(void* const* d_in, const int* in_sizes, int n_in,
                              void* d_out, int out_size, void* d_ws, size_t ws_size,
                              hipStream_t stream) {
  const float* x0 = (const float*)d_in[0];
  const int* ei = (const int*)d_in[1];
  const int* batch = (const int*)d_in[2];
  const int N = in_sizes[0] / 128;
  const int E = in_sizes[1] / 2;
  const int* src = ei;
  const int* dst = ei + E;
  const float* W[3][6];
  for (int li = 0; li < 3; li++)
    for (int k = 0; k < 6; k++) W[li][k] = (const float*)d_in[3 + li * 6 + k];
  const float* wo = (const float*)d_in[21];
  const float* bo = (const float*)d_in[22];
  float* out = (float*)d_out;

  // workspace layout
  float* agg = (float*)d_ws;                 // N*256
  float* h1 = agg + (size_t)N * 256;         // N*512
  float* h2 = h1 + (size_t)N * 512;          // N*512
  float* stats = h2 + (size_t)N * 512;       // 1024
  float* pooled = stats + 1024;              // 64*512
  int* deg = (int*)(pooled + 64 * 512);      // N
  int* rowstart = deg + N;                   // N+1
  int* cursor = rowstart + N + 1;            // N
  int* nbr = cursor + N;                     // E
  uintptr_t wp = (uintptr_t)(nbr + E);
  wp = (wp + 15) & ~(uintptr_t)15;
  unsigned short* wbuf = (unsigned short*)wp;

  const int dins[3] = {128, 128, 256};
  const int douts[3] = {128, 256, 512};

  unsigned short* WT[3][4];
  {
    unsigned short* p = wbuf;
    for (int li = 0; li < 3; li++) {
      size_t s1 = (size_t)dins[li] * douts[li];
      size_t s2 = (size_t)douts[li] * douts[li];
      WT[li][0] = p; p += s1;
      WT[li][1] = p; p += s1;
      WT[li][2] = p; p += s2;
      WT[li][3] = p; p += s2;
    }
  }
  for (int li = 0; li < 3; li++) {
    int e1 = dins[li] * douts[li];
    int e2 = douts[li] * douts[li];
    wprep_kernel<<<(e1 + 255) / 256, 256, 0, stream>>>(W[li][0], WT[li][0], WT[li][1], dins[li], douts[li]);
    wprep_kernel<<<(e2 + 255) / 256, 256, 0, stream>>>(W[li][2], WT[li][2], WT[li][3], douts[li], douts[li]);
  }

  // CSR build
  hipMemsetAsync(deg, 0, (size_t)N * sizeof(int), stream);
  hist_kernel<<<(E + 255) / 256, 256, 0, stream>>>(dst, deg, E);
  scan_kernel<<<1, 1024, 0, stream>>>(deg, rowstart, cursor, N);
  fill_kernel<<<(E + 255) / 256, 256, 0, stream>>>(src, dst, cursor, nbr, E);

  const int mblocks = (N + 63) / 64;
  const int mb8 = ((mblocks + 7) / 8) * 8;
  const float* xin = x0;
  for (int li = 0; li < 3; li++) {
    int Din = dins[li], Dout = douts[li];
    int gblocks = (N + 3) / 4;
    if (Din == 128)
      gather_agg_kernel<2><<<gblocks, 256, 0, stream>>>(xin, rowstart, nbr, agg, N);
    else
      gather_agg_kernel<4><<<gblocks, 256, 0, stream>>>(xin, rowstart, nbr, agg, N);
    int cbShift = (Dout == 128) ? 0 : (Dout == 256) ? 1 : 2;
    int nblocks = mb8 << cbShift;
    gemm_mfma_kernel<<<nblocks, 256, 0, stream>>>(agg, WT[li][0], WT[li][1], W[li][1], h1,
                                                  N, Din, Dout, mblocks, cbShift, 1, nullptr);
    hipMemsetAsync(stats, 0, 2 * Dout * sizeof(float), stream);
    gemm_mfma_kernel<<<nblocks, 256, 0, stream>>>(h1, WT[li][2], WT[li][3], W[li][3], h2,
                                                  N, Dout, Dout, mblocks, cbShift, 0, stats);
    bn_prep_kernel<<<(Dout + 255) / 256, 256, 0, stream>>>(stats, W[li][4], W[li][5], Dout, 1.0f / N);
    int odq = Dout >> 2;
    int odqs = (odq == 32) ? 5 : (odq == 64) ? 6 : 7;
    int t4 = N * odq;
    bn_apply_kernel<<<(t4 + 255) / 256, 256, 0, stream>>>(h2, stats, h1, t4, Dout, odqs);
    xin = h1;
  }
  pool_kernel<<<64, 128, 0, stream>>>(h1, batch, pooled, N);
  out_kernel<<<64, 64, 0, stream>>>(pooled, wo, bo, out);
}

// Round 5
// 432.238 us; speedup vs baseline: 6.3400x; 1.1936x over previous
//
#include <hip/hip_runtime.h>

typedef float f32x4 __attribute__((ext_vector_type(4)));
typedef short bf16x8 __attribute__((ext_vector_type(8)));

__device__ __forceinline__ unsigned short bf16r(float f) {
  unsigned int u = __float_as_uint(f);
  return (unsigned short)((u + 0x7FFFu + ((u >> 16) & 1u)) >> 16);
}
__device__ __forceinline__ float bf2f(unsigned short h) {
  return __uint_as_float((unsigned int)h << 16);
}

// ================= CSR build =================
__global__ __launch_bounds__(256) void hist_kernel(const int* __restrict__ dst,
                                                   int* __restrict__ deg, int E) {
  int e = blockIdx.x * 256 + threadIdx.x;
  if (e < E) atomicAdd(&deg[dst[e]], 1);
}

__global__ __launch_bounds__(1024) void scan_kernel(const int* __restrict__ deg,
                                                    int* __restrict__ rowstart,
                                                    int* __restrict__ cursor, int N) {
  __shared__ int sums[1024];
  const int t = threadIdx.x;
  const int CH = (N + 1023) >> 10;
  int local[32];
  int base = t * CH;
  int s = 0;
  for (int i = 0; i < CH; i++) {
    int idx = base + i;
    int v = (idx < N) ? deg[idx] : 0;
    local[i] = s;
    s += v;
  }
  sums[t] = s;
  __syncthreads();
  for (int off = 1; off < 1024; off <<= 1) {
    int add = (t >= off) ? sums[t - off] : 0;
    __syncthreads();
    sums[t] += add;
    __syncthreads();
  }
  int prefix = sums[t] - s;
  for (int i = 0; i < CH; i++) {
    int idx = base + i;
    if (idx < N) {
      int v = prefix + local[i];
      rowstart[idx] = v;
      cursor[idx] = v;
    }
  }
  if (t == 1023) rowstart[N] = sums[1023];
}

__global__ __launch_bounds__(256) void fill_kernel(const int* __restrict__ src,
                                                   const int* __restrict__ dst,
                                                   int* __restrict__ cursor,
                                                   int* __restrict__ nbr, int E) {
  int e = blockIdx.x * 256 + threadIdx.x;
  if (e >= E) return;
  int pos = atomicAdd(&cursor[dst[e]], 1);
  nbr[pos] = src[e];
}

// ================= gather aggregation =================
template <int C>
__global__ __launch_bounds__(256) void gather_agg_kernel(
    const float* __restrict__ x, const int* __restrict__ rowstart,
    const int* __restrict__ nbr, float* __restrict__ agg, int N) {
  constexpr int Din = 64 * C;
  const int wave = threadIdx.x >> 6;
  const int lane = threadIdx.x & 63;
  const int node = blockIdx.x * 4 + wave;
  if (node >= N) return;
  float acc[C];
  {
    const float* p = x + (size_t)node * Din + lane * C;
    if constexpr (C == 2) {
      float2 v = *(const float2*)p;
      acc[0] = v.x; acc[1] = v.y;
    } else {
      float4 v = *(const float4*)p;
      acc[0] = v.x; acc[1] = v.y; acc[2] = v.z; acc[3] = v.w;
    }
  }
  const int rs = rowstart[node], re = rowstart[node + 1];
  for (int e = rs; e < re; e++) {
    int s0 = nbr[e];
    const float* p0 = x + (size_t)s0 * Din + lane * C;
    if constexpr (C == 2) {
      float2 v0 = *(const float2*)p0;
      acc[0] += v0.x; acc[1] += v0.y;
    } else {
      float4 v0 = *(const float4*)p0;
      acc[0] += v0.x; acc[1] += v0.y; acc[2] += v0.z; acc[3] += v0.w;
    }
  }
  float* o = agg + (size_t)node * Din + lane * C;
  if constexpr (C == 2) {
    *(float2*)o = make_float2(acc[0], acc[1]);
  } else {
    *(float4*)o = make_float4(acc[0], acc[1], acc[2], acc[3]);
  }
}

// ================= weight prep: W[K][N] fp32 -> WT_hi/lo [N][K] bf16 =================
__global__ __launch_bounds__(256) void wprep_kernel(const float* __restrict__ W,
                                                    unsigned short* __restrict__ TH,
                                                    unsigned short* __restrict__ TL,
                                                    int K, int N) {
  int idx = blockIdx.x * 256 + threadIdx.x;
  if (idx >= K * N) return;
  int k = idx / N, n = idx - k * N;
  float v = W[idx];
  unsigned short h = bf16r(v);
  TH[(size_t)n * K + k] = h;
  TL[(size_t)n * K + k] = bf16r(v - bf2f(h));
}

// ================= MFMA GEMM: C = A[MxK] @ B[KxN] + bias, split-bf16 =================
__global__ __launch_bounds__(256) void gemm_mfma_kernel(
    const float* __restrict__ A, const unsigned short* __restrict__ BT_hi,
    const unsigned short* __restrict__ BT_lo, const float* __restrict__ bias,
    float* __restrict__ C, int M, int K, int N, int mblocks, int cbShift,
    int doRelu, float* __restrict__ stats) {
  __shared__ unsigned short Ah[8 * 512];
  __shared__ unsigned short Al[8 * 512];
  const int bid = blockIdx.x;
  const int xcd = bid & 7;
  const int q = bid >> 3;
  const int r = ((q >> cbShift) << 3) + xcd;
  const int cb = q & ((1 << cbShift) - 1);
  if (r >= mblocks) return;

  const int tid = threadIdx.x;
  const int lane = tid & 63;
  const int w = tid >> 6;
  const int rowBase = r * 64;
  const int colBase = cb * 128 + w * 32;

  f32x4 acc[4][2] = {};

  const int c0 = colBase + (lane & 15);
  const int kfrag = (lane >> 4) * 8;
  const int srow = tid >> 2;
  const int schunk = tid & 3;
  const size_t arowOff = (size_t)(rowBase + srow) * K;
  const bool srowOk = (rowBase + srow) < M;
  const int slane = (srow & 15) | (schunk << 4);
  const int sfrag = srow >> 4;

  for (int k0 = 0; k0 < K; k0 += 64) {
#pragma unroll
    for (int i = 0; i < 2; i++) {
      int kk = k0 + schunk * 8 + i * 32;
      float v[8];
      if (srowOk) {
        float4 a = *(const float4*)(A + arowOff + kk);
        float4 b = *(const float4*)(A + arowOff + kk + 4);
        v[0] = a.x; v[1] = a.y; v[2] = a.z; v[3] = a.w;
        v[4] = b.x; v[5] = b.y; v[6] = b.z; v[7] = b.w;
      } else {
#pragma unroll
        for (int j = 0; j < 8; j++) v[j] = 0.f;
      }
      bf16x8 h8, l8;
#pragma unroll
      for (int j = 0; j < 8; j++) {
        unsigned short h = bf16r(v[j]);
        h8[j] = (short)h;
        l8[j] = (short)bf16r(v[j] - bf2f(h));
      }
      int frag = i * 4 + sfrag;
      *(bf16x8*)(Ah + frag * 512 + slane * 8) = h8;
      *(bf16x8*)(Al + frag * 512 + slane * 8) = l8;
    }
    __syncthreads();
#pragma unroll
    for (int ks = 0; ks < 2; ks++) {
      int kidx = k0 + ks * 32 + kfrag;
      bf16x8 bh0 = *(const bf16x8*)(BT_hi + (size_t)c0 * K + kidx);
      bf16x8 bl0 = *(const bf16x8*)(BT_lo + (size_t)c0 * K + kidx);
      bf16x8 bh1 = *(const bf16x8*)(BT_hi + (size_t)(c0 + 16) * K + kidx);
      bf16x8 bl1 = *(const bf16x8*)(BT_lo + (size_t)(c0 + 16) * K + kidx);
#pragma unroll
      for (int fi = 0; fi < 4; fi++) {
        int frag = ks * 4 + fi;
        bf16x8 ah = *(const bf16x8*)(Ah + frag * 512 + lane * 8);
        bf16x8 al = *(const bf16x8*)(Al + frag * 512 + lane * 8);
        acc[fi][0] = __builtin_amdgcn_mfma_f32_16x16x32_bf16(ah, bh0, acc[fi][0], 0, 0, 0);
        acc[fi][0] = __builtin_amdgcn_mfma_f32_16x16x32_bf16(al, bh0, acc[fi][0], 0, 0, 0);
        acc[fi][0] = __builtin_amdgcn_mfma_f32_16x16x32_bf16(ah, bl0, acc[fi][0], 0, 0, 0);
        acc[fi][1] = __builtin_amdgcn_mfma_f32_16x16x32_bf16(ah, bh1, acc[fi][1], 0, 0, 0);
        acc[fi][1] = __builtin_amdgcn_mfma_f32_16x16x32_bf16(al, bh1, acc[fi][1], 0, 0, 0);
        acc[fi][1] = __builtin_amdgcn_mfma_f32_16x16x32_bf16(ah, bl1, acc[fi][1], 0, 0, 0);
      }
    }
    __syncthreads();
  }

  const float bias0 = bias[c0], bias1 = bias[c0 + 16];
  float s1[2] = {0.f, 0.f}, s2[2] = {0.f, 0.f};
  const int rbase = rowBase + (lane >> 4) * 4;
#pragma unroll
  for (int fi = 0; fi < 4; fi++) {
#pragma unroll
    for (int j = 0; j < 4; j++) {
      int row = rbase + fi * 16 + j;
      float v0 = acc[fi][0][j] + bias0;
      float v1 = acc[fi][1][j] + bias1;
      if (doRelu) { v0 = fmaxf(v0, 0.f); v1 = fmaxf(v1, 0.f); }
      if (row < M) {
        C[(size_t)row * N + c0] = v0;
        C[(size_t)row * N + c0 + 16] = v1;
        s1[0] += v0; s2[0] += v0 * v0;
        s1[1] += v1; s2[1] += v1 * v1;
      }
    }
  }
  if (stats) {
#pragma unroll
    for (int off = 16; off < 64; off <<= 1) {
      s1[0] += __shfl_xor(s1[0], off);
      s2[0] += __shfl_xor(s2[0], off);
      s1[1] += __shfl_xor(s1[1], off);
      s2[1] += __shfl_xor(s2[1], off);
    }
    if (lane < 16) {
      atomicAdd(&stats[c0], s1[0]);
      atomicAdd(&stats[N + c0], s2[0]);
      atomicAdd(&stats[c0 + 16], s1[1]);
      atomicAdd(&stats[N + c0 + 16], s2[1]);
    }
  }
}

// ================= BN fold =================
__global__ __launch_bounds__(256) void bn_prep_kernel(float* __restrict__ stats,
                                                      const float* __restrict__ gamma,
                                                      const float* __restrict__ beta,
                                                      int D, float invN) {
  int c = blockIdx.x * 256 + threadIdx.x;
  if (c >= D) return;
  float mean = stats[c] * invN;
  float var = stats[D + c] * invN - mean * mean;
  float sc = rsqrtf(var + 1e-5f) * gamma[c];
  stats[c] = sc;
  stats[D + c] = beta[c] - mean * sc;
}

// ================= BN apply + ReLU =================
__global__ __launch_bounds__(256) void bn_apply_kernel(
    const float* __restrict__ h, const float* __restrict__ stats,
    float* __restrict__ out, int total4, int D, int dqShift) {
  int idx = blockIdx.x * 256 + threadIdx.x;
  if (idx >= total4) return;
  int c4 = (idx & ((1 << dqShift) - 1)) << 2;
  float4 v = ((const float4*)h)[idx];
  float4 sc = *(const float4*)(stats + c4);
  float4 sh = *(const float4*)(stats + D + c4);
  float4 r;
  r.x = fmaxf(v.x * sc.x + sh.x, 0.f);
  r.y = fmaxf(v.y * sc.y + sh.y, 0.f);
  r.z = fmaxf(v.z * sc.z + sh.z, 0.f);
  r.w = fmaxf(v.w * sc.w + sh.w, 0.f);
  ((float4*)out)[idx] = r;
}

// ================= fused BN+ReLU+segment-mean pool (layer 3, D=512) =================
// grid = 64 graphs x 8 row-slices; pooled must be pre-zeroed.
__global__ __launch_bounds__(256) void bn_pool_kernel(
    const float* __restrict__ h, const float* __restrict__ stats,
    const int* __restrict__ batch, float* __restrict__ pooled, int N) {
  const int g = blockIdx.x >> 3;
  const int s = blockIdx.x & 7;
  __shared__ int s_lo, s_hi;
  if (threadIdx.x == 0) {
    int lo = 0, hi = N;
    while (lo < hi) { int m = (lo + hi) >> 1; if (batch[m] < g) lo = m + 1; else hi = m; }
    s_lo = lo;
    lo = 0; hi = N;
    while (lo < hi) { int m = (lo + hi) >> 1; if (batch[m] < g + 1) lo = m + 1; else hi = m; }
    s_hi = lo;
  }
  __syncthreads();
  const int lo = s_lo, hi = s_hi, len = hi - lo;
  if (len == 0) return;
  const int per = (len + 7) >> 3;
  const int rs = lo + s * per;
  const int re = min(rs + per, hi);
  if (rs >= re) return;
  const int t = threadIdx.x;  // channels 2t, 2t+1
  float2 sc = *(const float2*)(stats + 2 * t);
  float2 sh = *(const float2*)(stats + 512 + 2 * t);
  float ax = 0.f, ay = 0.f;
  for (int r = rs; r < re; r++) {
    float2 v = *(const float2*)(h + (size_t)r * 512 + 2 * t);
    ax += fmaxf(v.x * sc.x + sh.x, 0.f);
    ay += fmaxf(v.y * sc.y + sh.y, 0.f);
  }
  float inv = 1.f / (float)len;
  atomicAdd(&pooled[g * 512 + 2 * t], ax * inv);
  atomicAdd(&pooled[g * 512 + 2 * t + 1], ay * inv);
}

// ================= final projection =================
__global__ __launch_bounds__(64) void out_kernel(const float* __restrict__ pooled,
                                                 const float* __restrict__ wo,
                                                 const float* __restrict__ bo,
                                                 float* __restrict__ out) {
  int g = blockIdx.x, o = threadIdx.x;
  float acc = bo[o];
  for (int c = 0; c < 512; c++) acc += pooled[g * 512 + c] * wo[c * 64 + o];
  out[g * 64 + o] = fmaxf(acc, 0.f);
}

extern "C" void kernel_launch(void* const* d_in, const int* in_sizes, int n_in,
                              void* d_out, int out_size, void* d_ws, size_t ws_size,
                              hipStream_t stream) {
  const float* x0 = (const float*)d_in[0];
  const int* ei = (const int*)d_in[1];
  const int* batch = (const int*)d_in[2];
  const int N = in_sizes[0] / 128;
  const int E = in_sizes[1] / 2;
  const int* src = ei;
  const int* dst = ei + E;
  const float* W[3][6];
  for (int li = 0; li < 3; li++)
    for (int k = 0; k < 6; k++) W[li][k] = (const float*)d_in[3 + li * 6 + k];
  const float* wo = (const float*)d_in[21];
  const float* bo = (const float*)d_in[22];
  float* out = (float*)d_out;

  // workspace layout
  float* agg = (float*)d_ws;                 // N*256
  float* h1 = agg + (size_t)N * 256;         // N*512
  float* h2 = h1 + (size_t)N * 512;          // N*512
  float* stats = h2 + (size_t)N * 512;       // 1024
  float* pooled = stats + 1024;              // 64*512
  int* deg = (int*)(pooled + 64 * 512);      // N
  int* rowstart = deg + N;                   // N+1
  int* cursor = rowstart + N + 1;            // N
  int* nbr = cursor + N;                     // E
  uintptr_t wp = (uintptr_t)(nbr + E);
  wp = (wp + 15) & ~(uintptr_t)15;
  unsigned short* wbuf = (unsigned short*)wp;

  const int dins[3] = {128, 128, 256};
  const int douts[3] = {128, 256, 512};

  unsigned short* WT[3][4];
  {
    unsigned short* p = wbuf;
    for (int li = 0; li < 3; li++) {
      size_t s1 = (size_t)dins[li] * douts[li];
      size_t s2 = (size_t)douts[li] * douts[li];
      WT[li][0] = p; p += s1;
      WT[li][1] = p; p += s1;
      WT[li][2] = p; p += s2;
      WT[li][3] = p; p += s2;
    }
  }
  for (int li = 0; li < 3; li++) {
    int e1 = dins[li] * douts[li];
    int e2 = douts[li] * douts[li];
    wprep_kernel<<<(e1 + 255) / 256, 256, 0, stream>>>(W[li][0], WT[li][0], WT[li][1], dins[li], douts[li]);
    wprep_kernel<<<(e2 + 255) / 256, 256, 0, stream>>>(W[li][2], WT[li][2], WT[li][3], douts[li], douts[li]);
  }

  // CSR build
  hipMemsetAsync(deg, 0, (size_t)N * sizeof(int), stream);
  hist_kernel<<<(E + 255) / 256, 256, 0, stream>>>(dst, deg, E);
  scan_kernel<<<1, 1024, 0, stream>>>(deg, rowstart, cursor, N);
  fill_kernel<<<(E + 255) / 256, 256, 0, stream>>>(src, dst, cursor, nbr, E);

  const int mblocks = (N + 63) / 64;
  const int mb8 = ((mblocks + 7) / 8) * 8;
  const float* xin = x0;
  for (int li = 0; li < 3; li++) {
    int Din = dins[li], Dout = douts[li];
    int gblocks = (N + 3) / 4;
    if (Din == 128)
      gather_agg_kernel<2><<<gblocks, 256, 0, stream>>>(xin, rowstart, nbr, agg, N);
    else
      gather_agg_kernel<4><<<gblocks, 256, 0, stream>>>(xin, rowstart, nbr, agg, N);
    int cbShift = (Dout == 128) ? 0 : (Dout == 256) ? 1 : 2;
    int nblocks = mb8 << cbShift;
    gemm_mfma_kernel<<<nblocks, 256, 0, stream>>>(agg, WT[li][0], WT[li][1], W[li][1], h1,
                                                  N, Din, Dout, mblocks, cbShift, 1, nullptr);
    hipMemsetAsync(stats, 0, 2 * Dout * sizeof(float), stream);
    gemm_mfma_kernel<<<nblocks, 256, 0, stream>>>(h1, WT[li][2], WT[li][3], W[li][3], h2,
                                                  N, Dout, Dout, mblocks, cbShift, 0, stats);
    bn_prep_kernel<<<(Dout + 255) / 256, 256, 0, stream>>>(stats, W[li][4], W[li][5], Dout, 1.0f / N);
    if (li < 2) {
      int odq = Dout >> 2;
      int odqs = (odq == 32) ? 5 : (odq == 64) ? 6 : 7;
      int t4 = N * odq;
      bn_apply_kernel<<<(t4 + 255) / 256, 256, 0, stream>>>(h2, stats, h1, t4, Dout, odqs);
      xin = h1;
    } else {
      hipMemsetAsync(pooled, 0, 64 * 512 * sizeof(float), stream);
      bn_pool_kernel<<<64 * 8, 256, 0, stream>>>(h2, stats, batch, pooled, N);
    }
  }
  out_kernel<<<64, 64, 0, stream>>>(pooled, wo, bo, out);
}